// Round 1
// baseline (603.250 us; speedup 1.0000x reference)
//
#include <hip/hip_runtime.h>

typedef unsigned long long u64;

#define G_ 32          // B*H
#define W_ 64          // windows per group
#define N_ 256         // points per window
#define L_ 16384       // W_*N_ points per group
#define D_ 128         // dim
#define ONEHOT_ 33554432LL   // G_*L_*W_

// ---------------------------------------------------------------------------
// k1: per-window sums -> normalized init codebook c0.
// c0n: [g][w][d] (natural), c0t: [g][d4][w][4] (transposed, for LDS staging)
// ---------------------------------------------------------------------------
__global__ __launch_bounds__(256) void k1_sums(const float* __restrict__ x,
                                               float* __restrict__ c0n,
                                               float* __restrict__ c0t) {
  int blk = blockIdx.x;              // g*64 + w
  int g = blk >> 6, w = blk & 63;
  const float* xp = x + ((size_t)blk << 15);   // window base: N_*D_ = 32768 floats
  int t = threadIdx.x;
  int d4 = t & 31, r0 = t >> 5;      // d4: float4 slot of dim, r0: row group 0..7
  float4 acc = make_float4(0.f, 0.f, 0.f, 0.f);
  #pragma unroll 4
  for (int r = r0; r < N_; r += 8) {
    float4 v = *(const float4*)(xp + r * D_ + d4 * 4);
    acc.x += v.x; acc.y += v.y; acc.z += v.z; acc.w += v.w;
  }
  __shared__ float4 part[8][32];
  __shared__ double ssq[33];
  part[r0][d4] = acc;
  __syncthreads();
  if (t < 32) {
    float4 s = part[0][t];
    for (int r = 1; r < 8; ++r) {
      float4 v = part[r][t];
      s.x += v.x; s.y += v.y; s.z += v.z; s.w += v.w;
    }
    part[0][t] = s;
    ssq[t] = (double)s.x * s.x + (double)s.y * s.y + (double)s.z * s.z + (double)s.w * s.w;
  }
  __syncthreads();
  if (t == 0) {
    double tot = 0.0;
    for (int i = 0; i < 32; ++i) tot += ssq[i];
    ssq[32] = 1.0 / sqrt(tot);
  }
  __syncthreads();
  if (t < 32) {
    float rn = (float)ssq[32];
    float4 s = part[0][t];
    float4 c = make_float4(s.x * rn, s.y * rn, s.z * rn, s.w * rn);
    *(float4*)(c0n + ((size_t)blk << 7) + t * 4) = c;
    float* ct = c0t + ((size_t)g << 13) + t * 256 + w * 4;
    ct[0] = c.x; ct[1] = c.y; ct[2] = c.z; ct[3] = c.w;
  }
}

// ---------------------------------------------------------------------------
// k2: affinity pass. For each point: dot vs all 64 codebooks (lane = window),
// per-point argmax over w -> deterministic i64 fixed-point accumulation of
// assigned points per window; per-window running max over points -> packed
// u64 atomicMax (value-key || ~l so ties pick smallest l, numpy semantics).
// Block: 1024 thr = 16 waves, each wave 128 points (32 groups of 4).
// Grid: 32 g * 8 = 256 blocks.
// ---------------------------------------------------------------------------
__global__ __launch_bounds__(1024) void k2_assign(const float* __restrict__ x,
                                                  const float* __restrict__ c0t,
                                                  u64* __restrict__ deltaI,
                                                  u64* __restrict__ best) {
  __shared__ float ldsC[8192];       // [d4][w] float4-flattened codebooks (32 KiB)
  __shared__ u64   ldsD[8192];       // [w][d] fixed-point partials (64 KiB)
  __shared__ float ldsX[16][512];    // per-wave point staging (32 KiB)
  __shared__ int   ldsCnt[64];
  int g = blockIdx.x >> 3, bsub = blockIdx.x & 7;
  int t = threadIdx.x, lane = t & 63, wv = t >> 6;

  for (int i = t; i < 2048; i += 1024)
    ((float4*)ldsC)[i] = ((const float4*)(c0t + ((size_t)g << 13)))[i];
  for (int i = t; i < 8192; i += 1024) ldsD[i] = 0ULL;
  if (t < 64) ldsCnt[t] = 0;
  __syncthreads();

  const float* xg = x + ((size_t)g << 21);     // g * L_*D_
  int p0 = bsub * 2048 + wv * 128;
  float bestv = -3.0e38f;
  int bestl = 0;

  for (int grp = 0; grp < 32; ++grp) {
    int l0 = p0 + grp * 4;
    const float4* src = (const float4*)(xg + ((size_t)l0 << 7));
    float4* xw = (float4*)ldsX[wv];
    xw[lane]      = src[lane];        // 4 points * 128 floats, coalesced
    xw[lane + 64] = src[lane + 64];

    float4 s0 = make_float4(0.f,0.f,0.f,0.f), s1 = s0, s2 = s0, s3 = s0;
    #pragma unroll 8
    for (int d4 = 0; d4 < 32; ++d4) {
      float4 c4 = ((const float4*)ldsC)[(d4 << 6) + lane];  // conflict-free
      float4 x0 = xw[d4];           // broadcast
      float4 x1 = xw[32 + d4];
      float4 x2 = xw[64 + d4];
      float4 x3 = xw[96 + d4];
      s0.x += c4.x * x0.x; s0.y += c4.y * x0.y; s0.z += c4.z * x0.z; s0.w += c4.w * x0.w;
      s1.x += c4.x * x1.x; s1.y += c4.y * x1.y; s1.z += c4.z * x1.z; s1.w += c4.w * x1.w;
      s2.x += c4.x * x2.x; s2.y += c4.y * x2.y; s2.z += c4.z * x2.z; s2.w += c4.w * x2.w;
      s3.x += c4.x * x3.x; s3.y += c4.y * x3.y; s3.z += c4.z * x3.z; s3.w += c4.w * x3.w;
    }
    float aff[4];
    aff[0] = (s0.x + s0.y) + (s0.z + s0.w);
    aff[1] = (s1.x + s1.y) + (s1.z + s1.w);
    aff[2] = (s2.x + s2.y) + (s2.z + s2.w);
    aff[3] = (s3.x + s3.y) + (s3.z + s3.w);

    int a[4];
    #pragma unroll
    for (int p = 0; p < 4; ++p) {
      float v = aff[p]; int idx = lane;
      #pragma unroll
      for (int off = 32; off > 0; off >>= 1) {
        float v2 = __shfl_xor(v, off);
        int i2 = __shfl_xor(idx, off);
        if (v2 > v || (v2 == v && i2 < idx)) { v = v2; idx = i2; }
      }
      a[p] = idx;                                   // assignment of point l0+p
      if (aff[p] > bestv) { bestv = aff[p]; bestl = l0 + p; }  // per-window best
    }

    #pragma unroll
    for (int p = 0; p < 4; ++p) {
      float v0 = ldsX[wv][(p << 7) + lane];
      float v1 = ldsX[wv][(p << 7) + 64 + lane];
      long long i0 = __double2ll_rn((double)v0 * 4294967296.0);
      long long i1 = __double2ll_rn((double)v1 * 4294967296.0);
      int base = (a[p] << 7);
      atomicAdd(&ldsD[base + lane], (u64)i0);
      atomicAdd(&ldsD[base + 64 + lane], (u64)i1);
      if (lane == a[p]) atomicAdd(&ldsCnt[a[p]], 1);
    }
  }

  // per-window best -> global packed atomicMax (deterministic)
  {
    unsigned int key = __float_as_uint(bestv);
    key ^= (key & 0x80000000u) ? 0xFFFFFFFFu : 0x80000000u;
    u64 pk = ((u64)key << 32) | (u64)(0xFFFFFFFFu - (unsigned)bestl);
    atomicMax(&best[(g << 6) + lane], pk);
  }
  __syncthreads();

  // flush block partials (skip windows with no assigned points)
  int d = t & 127;
  for (int w = (t >> 7); w < 64; w += 8) {
    if (ldsCnt[w] > 0) {
      u64 v = ldsD[(w << 7) + d];
      if (v) atomicAdd(&deltaI[(((size_t)(g << 6) + w) << 7) + d], v);
    }
  }
}

// ---------------------------------------------------------------------------
// k3: finalize codebook: delta = assigned_sum + x[best_l]; l2norm; blend with
// c0 (gamma=0.5); l2norm; write c to d_out tail and transposed copy for k4.
// One block per (g,w), 128 threads (thread = d).
// ---------------------------------------------------------------------------
__global__ __launch_bounds__(128) void k3_final(const float* __restrict__ x,
                                                const float* __restrict__ c0n,
                                                const u64* __restrict__ deltaI,
                                                const u64* __restrict__ best,
                                                float* __restrict__ cOut,
                                                float* __restrict__ ct) {
  int blk = blockIdx.x;
  int g = blk >> 6, w = blk & 63;
  int d = threadIdx.x;
  u64 pk = best[blk];
  int bl = (int)(0xFFFFFFFFu - (unsigned)(pk & 0xFFFFFFFFull));
  float xb = x[((size_t)g << 21) + ((size_t)bl << 7) + d];
  long long di = (long long)deltaI[((size_t)blk << 7) + d];
  double delta = (double)di * (1.0 / 4294967296.0) + (double)xb;

  __shared__ double red[128];
  __shared__ double inv;
  red[d] = delta * delta;
  __syncthreads();
  for (int s = 64; s > 0; s >>= 1) {
    if (d < s) red[d] += red[d + s];
    __syncthreads();
  }
  if (d == 0) inv = 1.0 / sqrt(red[0]);
  __syncthreads();
  float dn = (float)(delta * inv);
  float b2 = 0.5f * c0n[((size_t)blk << 7) + d] + 0.5f * dn;
  __syncthreads();
  red[d] = (double)b2 * b2;
  __syncthreads();
  for (int s = 64; s > 0; s >>= 1) {
    if (d < s) red[d] += red[d + s];
    __syncthreads();
  }
  if (d == 0) inv = 1.0 / sqrt(red[0]);
  __syncthreads();
  float cf = b2 * (float)inv;
  cOut[((size_t)blk << 7) + d] = cf;
  ct[((size_t)g << 13) + ((size_t)(d >> 2) << 8) + (w << 2) + (d & 3)] = cf;
}

// ---------------------------------------------------------------------------
// k4: final cos_sim vs final codebooks, argmax over w, one-hot write.
// Block 1024 thr = 16 waves, each wave 64 points. Grid: 32 g * 16 = 512.
// ---------------------------------------------------------------------------
__global__ __launch_bounds__(1024) void k4_onehot(const float* __restrict__ x,
                                                  const float* __restrict__ ct,
                                                  float* __restrict__ out) {
  __shared__ float ldsC[8192];
  __shared__ float ldsX[16][512];
  int g = blockIdx.x >> 4, bsub = blockIdx.x & 15;
  int t = threadIdx.x, lane = t & 63, wv = t >> 6;
  for (int i = t; i < 2048; i += 1024)
    ((float4*)ldsC)[i] = ((const float4*)(ct + ((size_t)g << 13)))[i];
  __syncthreads();
  const float* xg = x + ((size_t)g << 21);
  int p0 = bsub * 1024 + wv * 64;
  for (int grp = 0; grp < 16; ++grp) {
    int l0 = p0 + grp * 4;
    const float4* src = (const float4*)(xg + ((size_t)l0 << 7));
    float4* xw = (float4*)ldsX[wv];
    xw[lane]      = src[lane];
    xw[lane + 64] = src[lane + 64];

    float4 s0 = make_float4(0.f,0.f,0.f,0.f), s1 = s0, s2 = s0, s3 = s0;
    #pragma unroll 8
    for (int d4 = 0; d4 < 32; ++d4) {
      float4 c4 = ((const float4*)ldsC)[(d4 << 6) + lane];
      float4 x0 = xw[d4];
      float4 x1 = xw[32 + d4];
      float4 x2 = xw[64 + d4];
      float4 x3 = xw[96 + d4];
      s0.x += c4.x * x0.x; s0.y += c4.y * x0.y; s0.z += c4.z * x0.z; s0.w += c4.w * x0.w;
      s1.x += c4.x * x1.x; s1.y += c4.y * x1.y; s1.z += c4.z * x1.z; s1.w += c4.w * x1.w;
      s2.x += c4.x * x2.x; s2.y += c4.y * x2.y; s2.z += c4.z * x2.z; s2.w += c4.w * x2.w;
      s3.x += c4.x * x3.x; s3.y += c4.y * x3.y; s3.z += c4.z * x3.z; s3.w += c4.w * x3.w;
    }
    float aff[4];
    aff[0] = (s0.x + s0.y) + (s0.z + s0.w);
    aff[1] = (s1.x + s1.y) + (s1.z + s1.w);
    aff[2] = (s2.x + s2.y) + (s2.z + s2.w);
    aff[3] = (s3.x + s3.y) + (s3.z + s3.w);

    #pragma unroll
    for (int p = 0; p < 4; ++p) {
      float v = aff[p]; int idx = lane;
      #pragma unroll
      for (int off = 32; off > 0; off >>= 1) {
        float v2 = __shfl_xor(v, off);
        int i2 = __shfl_xor(idx, off);
        if (v2 > v || (v2 == v && i2 < idx)) { v = v2; idx = i2; }
      }
      out[((size_t)(g * L_ + l0 + p) << 6) + lane] = (lane == idx) ? 1.0f : 0.0f;
    }
  }
}

extern "C" void kernel_launch(void* const* d_in, const int* in_sizes, int n_in,
                              void* d_out, int out_size, void* d_ws, size_t ws_size,
                              hipStream_t stream) {
  const float* x = (const float*)d_in[0];
  float* out = (float*)d_out;
  char* ws = (char*)d_ws;
  float* c0n = (float*)(ws);                       // 1 MiB  [g][w][d]
  float* c0t = (float*)(ws + (1u << 20));          // 1 MiB  [g][d4][w][4]
  float* ct  = (float*)(ws + (2u << 20));          // 1 MiB  [g][d4][w][4] final
  u64* deltaI = (u64*)(ws + (3u << 20));           // 2 MiB  [g][w][d] i64 fixed-point
  u64* best   = (u64*)(ws + (5u << 20));           // 16 KiB [g][w] packed (key||~l)

  // zero the accumulators (0 packs as -inf sentinel for best)
  hipMemsetAsync(ws + (3u << 20), 0, (2u << 20) + 16384, stream);

  hipLaunchKernelGGL(k1_sums,   dim3(2048), dim3(256),  0, stream, x, c0n, c0t);
  hipLaunchKernelGGL(k2_assign, dim3(256),  dim3(1024), 0, stream, x, c0t, deltaI, best);
  hipLaunchKernelGGL(k3_final,  dim3(2048), dim3(128),  0, stream, x, c0n, deltaI, best,
                     out + ONEHOT_, ct);
  hipLaunchKernelGGL(k4_onehot, dim3(512),  dim3(1024), 0, stream, x, ct, out);
}